// Round 3
// baseline (1808.384 us; speedup 1.0000x reference)
//
#include <hip/hip_runtime.h>

// HPWL via order-preserving float->uint encoding: all four reductions are
// atomicMax(unsigned); mins stored as max of complement. Identity = 0, so one
// memset(0) initializes and slot.x==0 flags "empty net".
//
// R2 structure:
//  - Per-net state interleaved as uint4 {max_x, ~min_x, max_y, ~min_y} so a
//    pin's 4 atomics hit ONE cache line (was 4 random lines in 4 arrays:
//    WRITE_SIZE showed 40M x 32B = 1.28 GB of L2<->fabric thrash).
//  - Nets processed in 2 passes (range-chunked) so the per-pass atomic
//    working set (24 MB) fits in the 32 MB aggregate L2.
//  - Input streams loaded non-temporally to avoid evicting atomic lines.

typedef float  v4f __attribute__((ext_vector_type(4)));
typedef int    v4i __attribute__((ext_vector_type(4)));

__device__ __forceinline__ unsigned enc(float f) {
    unsigned u = __float_as_uint(f);
    return u ^ ((unsigned)((int)u >> 31) | 0x80000000u);
}
__device__ __forceinline__ float dec(unsigned u) {
    unsigned b = (u & 0x80000000u) ? (u ^ 0x80000000u) : ~u;
    return __uint_as_float(b);
}

__device__ __forceinline__ void upd(unsigned* __restrict__ nets,
                                    float x, float y, int net, int lo, int hi) {
    if (net < lo || net >= hi) return;
    unsigned ex = enc(x), ey = enc(y);
    unsigned* base = nets + ((size_t)net << 2);
    atomicMax(base + 0, ex);
    atomicMax(base + 1, ~ex);
    atomicMax(base + 2, ey);
    atomicMax(base + 3, ~ey);
}

__global__ void pin_kernel(const v4f* __restrict__ px,
                           const v4f* __restrict__ py,
                           const v4i* __restrict__ p2n,
                           unsigned* __restrict__ nets,
                           int n4, int lo, int hi) {
    int i = blockIdx.x * blockDim.x + threadIdx.x;
    if (i >= n4) return;
    v4f x = __builtin_nontemporal_load(px + i);
    v4f y = __builtin_nontemporal_load(py + i);
    v4i net = __builtin_nontemporal_load(p2n + i);
    upd(nets, x.x, y.x, net.x, lo, hi);
    upd(nets, x.y, y.y, net.y, lo, hi);
    upd(nets, x.z, y.z, net.z, lo, hi);
    upd(nets, x.w, y.w, net.w, lo, hi);
}

// Tail for num_pins % 4 != 0 (not hit at 10M).
__global__ void pin_tail_kernel(const float* __restrict__ pos,
                                const int* __restrict__ p2n,
                                unsigned* __restrict__ nets,
                                int start, int num_pins, int lo, int hi) {
    int i = start + blockIdx.x * blockDim.x + threadIdx.x;
    if (i >= num_pins) return;
    upd(nets, pos[i], pos[i + num_pins], p2n[i], lo, hi);
}

__global__ void net_kernel(const uint4* __restrict__ nets,
                           const int* __restrict__ mask,   // jnp bool -> int32 words
                           float* __restrict__ out, int num_nets) {
    int i = blockIdx.x * blockDim.x + threadIdx.x;
    float h = 0.0f;
    if (i < num_nets) {
        uint4 v = nets[i];   // {max_x, ~min_x, max_y, ~min_y}
        if (v.x != 0u && mask[i] != 0) {
            float xmax = dec(v.x);
            float xmin = dec(~v.y);
            float ymax = dec(v.z);
            float ymin = dec(~v.w);
            h = (xmax - xmin) + (ymax - ymin);
        }
    }
    #pragma unroll
    for (int off = 32; off > 0; off >>= 1)
        h += __shfl_down(h, off);
    __shared__ float s[4];
    int wid = threadIdx.x >> 6;
    if ((threadIdx.x & 63) == 0) s[wid] = h;
    __syncthreads();
    if (threadIdx.x == 0) {
        float t = s[0] + s[1] + s[2] + s[3];
        atomicAdd(out, t);
    }
}

extern "C" void kernel_launch(void* const* d_in, const int* in_sizes, int n_in,
                              void* d_out, int out_size, void* d_ws, size_t ws_size,
                              hipStream_t stream) {
    const float* pos = (const float*)d_in[0];
    const int* p2n = (const int*)d_in[1];
    const int* mask = (const int*)d_in[2];
    const int num_pins = in_sizes[0] / 2;
    const int num_nets = in_sizes[2];

    unsigned* nets = (unsigned*)d_ws;   // uint4 per net

    hipMemsetAsync(d_ws, 0, (size_t)num_nets * 4 * sizeof(unsigned), stream);
    hipMemsetAsync(d_out, 0, sizeof(float), stream);

    const int threads = 256;
    const int n4 = num_pins / 4;
    const int NPASS = 2;   // 24 MB atomic working set per pass < 32 MB agg L2
    const int chunk = (num_nets + NPASS - 1) / NPASS;

    for (int p = 0; p < NPASS; ++p) {
        int lo = p * chunk;
        int hi = min(num_nets, lo + chunk);
        if (n4 > 0) {
            int blocks = (n4 + threads - 1) / threads;
            pin_kernel<<<blocks, threads, 0, stream>>>(
                (const v4f*)pos, (const v4f*)(pos + num_pins), (const v4i*)p2n,
                nets, n4, lo, hi);
        }
        const int tail_start = n4 * 4;
        if (tail_start < num_pins) {
            int tail = num_pins - tail_start;
            pin_tail_kernel<<<(tail + threads - 1) / threads, threads, 0, stream>>>(
                pos, p2n, nets, tail_start, num_pins, lo, hi);
        }
    }
    net_kernel<<<(num_nets + threads - 1) / threads, threads, 0, stream>>>(
        (const uint4*)nets, mask, (float*)d_out, num_nets);
}

// Round 4
// 431.860 us; speedup vs baseline: 4.1874x; 4.1874x over previous
//
#include <hip/hip_runtime.h>

// HPWL, binned counting-sort structure (R4).
//
// R2/R3 post-mortem: device-scope global atomics are pinned at ~26.7 G/s on
// this chip regardless of layout/chunking (VALUBusy 0.4%, HBM 11%) — 40M
// atomics => ~1.5 ms floor. So: eliminate them. Bin pins by net-range into
// buckets of 2048 nets (exact counting-sort layout, no capacity slop), then
// reduce each bucket in a 32 KB LDS tile with LDS atomics (banks process 64
// lanes in parallel), one global atomicAdd per block at the end.
//
// Order-preserving float->uint encoding: max via atomicMax(enc), min via
// atomicMax(~enc); identity 0; enc never 0 for real inputs => tile.x==0
// flags "empty net" (replaces counts>0). net_mask arrives as int32 words.

#define BK_SHIFT 11
#define BK_NETS  2048                 // nets per bucket
#define MAX_BK   2048                 // max buckets (LDS hist/cursor arrays)
#define CHUNK    20480                // pins per scatter block (mult of 1024)
#define TPB      256

typedef float v4f __attribute__((ext_vector_type(4)));
typedef int   v4i __attribute__((ext_vector_type(4)));

__device__ __forceinline__ unsigned enc(float f) {
    unsigned u = __float_as_uint(f);
    return u ^ ((unsigned)((int)u >> 31) | 0x80000000u);
}
__device__ __forceinline__ float dec(unsigned u) {
    unsigned b = (u & 0x80000000u) ? (u ^ 0x80000000u) : ~u;
    return __uint_as_float(b);
}

// ---------------- Phase A: per-block bucket histogram ----------------
__global__ void histo_kernel(const int* __restrict__ p2n,
                             unsigned* __restrict__ counts,  // [NB][NBK] b-major
                             int P, int NBK) {
    int b = blockIdx.x;
    int pstart = b * CHUNK;
    int pend = min(P, pstart + CHUNK);
    __shared__ unsigned hist[MAX_BK];
    for (int k = threadIdx.x; k < NBK; k += TPB) hist[k] = 0;
    __syncthreads();
    int nv = (pend - pstart) >> 2;
    for (int g = threadIdx.x; g < nv; g += TPB) {
        int p = pstart + (g << 2);
        v4i nets = *(const v4i*)(p2n + p);
        atomicAdd(&hist[nets.x >> BK_SHIFT], 1u);
        atomicAdd(&hist[nets.y >> BK_SHIFT], 1u);
        atomicAdd(&hist[nets.z >> BK_SHIFT], 1u);
        atomicAdd(&hist[nets.w >> BK_SHIFT], 1u);
    }
    for (int p = pstart + (nv << 2) + threadIdx.x; p < pend; p += TPB)
        atomicAdd(&hist[p2n[p] >> BK_SHIFT], 1u);
    __syncthreads();
    for (int k = threadIdx.x; k < NBK; k += TPB)
        counts[(size_t)b * NBK + k] = hist[k];
}

// ---------------- K1: per-bucket exclusive scan over blocks ----------------
__global__ void scan_blocks_kernel(unsigned* __restrict__ counts,  // in: counts, out: excl
                                   unsigned* __restrict__ totals,
                                   int NB, int NBK) {
    int k = blockIdx.x * blockDim.x + threadIdx.x;
    if (k >= NBK) return;
    unsigned run = 0;
    #pragma unroll 8
    for (int b = 0; b < NB; ++b) {
        size_t idx = (size_t)b * NBK + k;
        unsigned v = counts[idx];
        counts[idx] = run;
        run += v;
    }
    totals[k] = run;
}

// ---------------- K2: exclusive scan over bucket totals ----------------
__global__ void scan_buckets_kernel(const unsigned* __restrict__ totals,
                                    unsigned* __restrict__ bucketBase, int NBK) {
    __shared__ unsigned s[TPB];
    int tid = threadIdx.x;
    int SEG = (NBK + TPB - 1) / TPB;
    int st = tid * SEG, en = min(NBK, st + SEG);
    unsigned sum = 0;
    for (int i = st; i < en; ++i) sum += totals[i];
    s[tid] = sum;
    __syncthreads();
    for (int off = 1; off < TPB; off <<= 1) {
        unsigned v = (tid >= off) ? s[tid - off] : 0u;
        __syncthreads();
        s[tid] += v;
        __syncthreads();
    }
    unsigned run = s[tid] - sum;   // exclusive base for this segment
    for (int i = st; i < en; ++i) {
        bucketBase[i] = run;
        run += totals[i];
    }
}

// ---------------- Phase C: scatter records ----------------
__global__ void scatter_kernel(const float* __restrict__ pos,
                               const int* __restrict__ p2n,
                               const unsigned* __restrict__ excl,        // [NB][NBK]
                               const unsigned* __restrict__ bucketBase,  // [NBK]
                               uint4* __restrict__ recs,
                               int P, int NBK) {
    int b = blockIdx.x;
    int pstart = b * CHUNK;
    int pend = min(P, pstart + CHUNK);
    __shared__ unsigned cursor[MAX_BK];
    for (int k = threadIdx.x; k < NBK; k += TPB)
        cursor[k] = bucketBase[k] + excl[(size_t)b * NBK + k];
    __syncthreads();
    int nv = (pend - pstart) >> 2;
    for (int g = threadIdx.x; g < nv; g += TPB) {
        int p = pstart + (g << 2);
        v4i nets = *(const v4i*)(p2n + p);
        v4f xs = *(const v4f*)(pos + p);
        v4f ys = *(const v4f*)(pos + P + p);
        #pragma unroll
        for (int j = 0; j < 4; ++j) {
            int net = nets[j];
            unsigned off = atomicAdd(&cursor[net >> BK_SHIFT], 1u);
            uint4 r;
            r.x = enc(xs[j]);
            r.y = enc(ys[j]);
            r.z = (unsigned)(net & (BK_NETS - 1));
            r.w = 0u;
            recs[off] = r;
        }
    }
    for (int p = pstart + (nv << 2) + threadIdx.x; p < pend; p += TPB) {
        int net = p2n[p];
        unsigned off = atomicAdd(&cursor[net >> BK_SHIFT], 1u);
        uint4 r;
        r.x = enc(pos[p]);
        r.y = enc(pos[P + p]);
        r.z = (unsigned)(net & (BK_NETS - 1));
        r.w = 0u;
        recs[off] = r;
    }
}

// ---------------- Phase D: per-bucket LDS reduce ----------------
__global__ void reduce_kernel(const uint4* __restrict__ recs,
                              const unsigned* __restrict__ totals,
                              const unsigned* __restrict__ bucketBase,
                              const int* __restrict__ mask,
                              float* __restrict__ out, int num_nets) {
    int k = blockIdx.x;
    __shared__ unsigned tile[4 * BK_NETS];   // SoA planes: ex, ~ex, ey, ~ey (32 KB)
    for (int i = threadIdx.x; i < 4 * BK_NETS; i += TPB) tile[i] = 0;
    __syncthreads();
    unsigned base = bucketBase[k];
    unsigned cnt = totals[k];
    for (unsigned i = base + threadIdx.x; i < base + cnt; i += TPB) {
        uint4 r = recs[i];
        atomicMax(&tile[r.z], r.x);
        atomicMax(&tile[BK_NETS + r.z], ~r.x);
        atomicMax(&tile[2 * BK_NETS + r.z], r.y);
        atomicMax(&tile[3 * BK_NETS + r.z], ~r.y);
    }
    __syncthreads();
    int gbase = k << BK_SHIFT;
    int nthis = min(BK_NETS, num_nets - gbase);
    float h = 0.0f;
    for (int n = threadIdx.x; n < nthis; n += TPB) {
        unsigned a = tile[n];
        if (a != 0u && mask[gbase + n] != 0) {
            float xmax = dec(a);
            float xmin = dec(~tile[BK_NETS + n]);
            float ymax = dec(tile[2 * BK_NETS + n]);
            float ymin = dec(~tile[3 * BK_NETS + n]);
            h += (xmax - xmin) + (ymax - ymin);
        }
    }
    #pragma unroll
    for (int off = 32; off > 0; off >>= 1)
        h += __shfl_down(h, off);
    __shared__ float s[TPB / 64];
    int wid = threadIdx.x >> 6;
    if ((threadIdx.x & 63) == 0) s[wid] = h;
    __syncthreads();
    if (threadIdx.x == 0) {
        float t = 0.0f;
        for (int w = 0; w < TPB / 64; ++w) t += s[w];
        atomicAdd(out, t);
    }
}

// ---------------- Fallback: R2-style global-atomic path ----------------
__device__ __forceinline__ void upd(unsigned* __restrict__ nets,
                                    float x, float y, int net) {
    unsigned ex = enc(x), ey = enc(y);
    unsigned* base = nets + ((size_t)net << 2);
    atomicMax(base + 0, ex);
    atomicMax(base + 1, ~ex);
    atomicMax(base + 2, ey);
    atomicMax(base + 3, ~ey);
}

__global__ void fb_pin_kernel(const float* __restrict__ pos,
                              const int* __restrict__ p2n,
                              unsigned* __restrict__ nets, int num_pins) {
    int i = blockIdx.x * blockDim.x + threadIdx.x;
    if (i >= num_pins) return;
    upd(nets, pos[i], pos[i + num_pins], p2n[i]);
}

__global__ void fb_net_kernel(const uint4* __restrict__ nets,
                              const int* __restrict__ mask,
                              float* __restrict__ out, int num_nets) {
    int i = blockIdx.x * blockDim.x + threadIdx.x;
    float h = 0.0f;
    if (i < num_nets) {
        uint4 v = nets[i];
        if (v.x != 0u && mask[i] != 0) {
            h = (dec(v.x) - dec(~v.y)) + (dec(v.z) - dec(~v.w));
        }
    }
    #pragma unroll
    for (int off = 32; off > 0; off >>= 1)
        h += __shfl_down(h, off);
    __shared__ float s[4];
    int wid = threadIdx.x >> 6;
    if ((threadIdx.x & 63) == 0) s[wid] = h;
    __syncthreads();
    if (threadIdx.x == 0)
        atomicAdd(out, s[0] + s[1] + s[2] + s[3]);
}

extern "C" void kernel_launch(void* const* d_in, const int* in_sizes, int n_in,
                              void* d_out, int out_size, void* d_ws, size_t ws_size,
                              hipStream_t stream) {
    const float* pos = (const float*)d_in[0];
    const int* p2n = (const int*)d_in[1];
    const int* mask = (const int*)d_in[2];
    const int P = in_sizes[0] / 2;
    const int N = in_sizes[2];

    const int NBK = (N + BK_NETS - 1) >> BK_SHIFT;
    const int NB = (P + CHUNK - 1) / CHUNK;

    // ws layout: recs[P] (16B each) | counts[NB*NBK] | totals[NBK] | bucketBase[NBK]
    size_t recs_bytes = (size_t)P * sizeof(uint4);
    size_t counts_bytes = (size_t)NB * NBK * sizeof(unsigned);
    size_t need = recs_bytes + counts_bytes + 2 * (size_t)NBK * sizeof(unsigned) + 256;

    hipMemsetAsync(d_out, 0, sizeof(float), stream);

    if (NBK <= MAX_BK && (P & 3) == 0 && ws_size >= need) {
        uint4* recs = (uint4*)d_ws;
        unsigned* counts = (unsigned*)((char*)d_ws + recs_bytes);
        unsigned* totals = counts + (size_t)NB * NBK;
        unsigned* bucketBase = totals + NBK;

        histo_kernel<<<NB, TPB, 0, stream>>>(p2n, counts, P, NBK);
        scan_blocks_kernel<<<(NBK + TPB - 1) / TPB, TPB, 0, stream>>>(counts, totals, NB, NBK);
        scan_buckets_kernel<<<1, TPB, 0, stream>>>(totals, bucketBase, NBK);
        scatter_kernel<<<NB, TPB, 0, stream>>>(pos, p2n, counts, bucketBase, recs, P, NBK);
        reduce_kernel<<<NBK, TPB, 0, stream>>>(recs, totals, bucketBase, mask,
                                               (float*)d_out, N);
    } else {
        // Fallback: global-atomic path (correct, slower)
        unsigned* nets = (unsigned*)d_ws;
        hipMemsetAsync(d_ws, 0, (size_t)N * 4 * sizeof(unsigned), stream);
        fb_pin_kernel<<<(P + TPB - 1) / TPB, TPB, 0, stream>>>(pos, p2n, nets, P);
        fb_net_kernel<<<(N + TPB - 1) / TPB, TPB, 0, stream>>>((const uint4*)nets, mask,
                                                               (float*)d_out, N);
    }
}

// Round 5
// 372.625 us; speedup vs baseline: 4.8531x; 1.1590x over previous
//
#include <hip/hip_runtime.h>

// HPWL, binned counting-sort (R5).
//
// R4 post-mortem: scatter was grid-limited (489 blocks -> 17% occupancy) and
// wrote 2x its ideal bytes (partial-line amplification on scattered 16B
// stores). R5: CHUNK 20480->5120 (1954 blocks), 8-byte packed records
// (26-bit x-prefix | 27-bit y-prefix | 11-bit local net; truncation of the
// order-preserving encoding is monotone => min/max consistent, error ~2e5
// vs 1.9e8 threshold), and a two-level scan so the inter-block prefix sum
// doesn't serialize over 1954 iterations.
//
// Encoding: enc(f) order-preserving float->uint; max via atomicMax(enc),
// min via atomicMax(~enc); identity 0; tile.x==0 flags empty net.
// net_mask arrives as int32 words.

#define BK_SHIFT 11
#define BK_NETS  2048
#define MAX_BK   2048
#define CHUNK    5120
#define TILE_B   128                  // blocks per scan tile
#define TPB      256

typedef float v4f __attribute__((ext_vector_type(4)));
typedef int   v4i __attribute__((ext_vector_type(4)));

__device__ __forceinline__ unsigned enc(float f) {
    unsigned u = __float_as_uint(f);
    return u ^ ((unsigned)((int)u >> 31) | 0x80000000u);
}
__device__ __forceinline__ float dec(unsigned u) {
    unsigned b = (u & 0x80000000u) ? (u ^ 0x80000000u) : ~u;
    return __uint_as_float(b);
}

// ---------------- Phase A: per-block bucket histogram ----------------
__global__ void histo_kernel(const int* __restrict__ p2n,
                             unsigned* __restrict__ counts,  // [NB][NBK]
                             int P, int NBK) {
    int b = blockIdx.x;
    int pstart = b * CHUNK;
    int pend = min(P, pstart + CHUNK);
    __shared__ unsigned hist[MAX_BK];
    for (int k = threadIdx.x; k < NBK; k += TPB) hist[k] = 0;
    __syncthreads();
    int nv = (pend - pstart) >> 2;
    for (int g = threadIdx.x; g < nv; g += TPB) {
        int p = pstart + (g << 2);
        v4i nets = *(const v4i*)(p2n + p);
        atomicAdd(&hist[nets.x >> BK_SHIFT], 1u);
        atomicAdd(&hist[nets.y >> BK_SHIFT], 1u);
        atomicAdd(&hist[nets.z >> BK_SHIFT], 1u);
        atomicAdd(&hist[nets.w >> BK_SHIFT], 1u);
    }
    for (int p = pstart + (nv << 2) + threadIdx.x; p < pend; p += TPB)
        atomicAdd(&hist[p2n[p] >> BK_SHIFT], 1u);
    __syncthreads();
    for (int k = threadIdx.x; k < NBK; k += TPB)
        counts[(size_t)b * NBK + k] = hist[k];
}

// ---------------- Scan level 1: per-(tile,bucket) partial sums ----------------
__global__ void partial_kernel(const unsigned* __restrict__ counts,
                               unsigned* __restrict__ tp,   // [NT][NBK]
                               int NB, int NBK) {
    int k = blockIdx.x * blockDim.x + threadIdx.x;
    int t = blockIdx.y;
    if (k >= NBK) return;
    int b0 = t * TILE_B, b1 = min(NB, b0 + TILE_B);
    unsigned s = 0;
    for (int b = b0; b < b1; ++b) s += counts[(size_t)b * NBK + k];
    tp[(size_t)t * NBK + k] = s;
}

// ---------------- Scan level 2: exclusive over tiles (per bucket) ----------------
__global__ void tile_scan_kernel(unsigned* __restrict__ tp,
                                 unsigned* __restrict__ totals,
                                 int NT, int NBK) {
    int k = blockIdx.x * blockDim.x + threadIdx.x;
    if (k >= NBK) return;
    unsigned run = 0;
    for (int t = 0; t < NT; ++t) {
        size_t idx = (size_t)t * NBK + k;
        unsigned v = tp[idx];
        tp[idx] = run;
        run += v;
    }
    totals[k] = run;
}

// ---------------- Scan level 3: exclusive over bucket totals ----------------
__global__ void scan_buckets_kernel(const unsigned* __restrict__ totals,
                                    unsigned* __restrict__ bucketBase, int NBK) {
    __shared__ unsigned s[TPB];
    int tid = threadIdx.x;
    int SEG = (NBK + TPB - 1) / TPB;
    int st = tid * SEG, en = min(NBK, st + SEG);
    unsigned sum = 0;
    for (int i = st; i < en; ++i) sum += totals[i];
    s[tid] = sum;
    __syncthreads();
    for (int off = 1; off < TPB; off <<= 1) {
        unsigned v = (tid >= off) ? s[tid - off] : 0u;
        __syncthreads();
        s[tid] += v;
        __syncthreads();
    }
    unsigned run = s[tid] - sum;
    for (int i = st; i < en; ++i) {
        bucketBase[i] = run;
        run += totals[i];
    }
}

// ---------------- Scan level 4: exclusive within tile, in place ----------------
__global__ void exclify_kernel(unsigned* __restrict__ counts,
                               const unsigned* __restrict__ tp,
                               int NB, int NBK) {
    int k = blockIdx.x * blockDim.x + threadIdx.x;
    int t = blockIdx.y;
    if (k >= NBK) return;
    int b0 = t * TILE_B, b1 = min(NB, b0 + TILE_B);
    unsigned run = tp[(size_t)t * NBK + k];
    for (int b = b0; b < b1; ++b) {
        size_t idx = (size_t)b * NBK + k;
        unsigned v = counts[idx];
        counts[idx] = run;
        run += v;
    }
}

// ---------------- Phase C: scatter 8B packed records ----------------
__device__ __forceinline__ uint2 pack_rec(float x, float y, int net) {
    unsigned ex = enc(x), ey = enc(y);
    unsigned nl = (unsigned)net & (BK_NETS - 1);
    uint2 r;
    r.x = (ex & 0xFFFFFFC0u) | (nl >> 5);   // x prefix 26b | net hi 6
    r.y = (ey & 0xFFFFFFE0u) | (nl & 31u);  // y prefix 27b | net lo 5
    return r;
}

__global__ void scatter_kernel(const float* __restrict__ pos,
                               const int* __restrict__ p2n,
                               const unsigned* __restrict__ excl,        // [NB][NBK]
                               const unsigned* __restrict__ bucketBase,  // [NBK]
                               uint2* __restrict__ recs,
                               int P, int NBK) {
    int b = blockIdx.x;
    int pstart = b * CHUNK;
    int pend = min(P, pstart + CHUNK);
    __shared__ unsigned cursor[MAX_BK];
    for (int k = threadIdx.x; k < NBK; k += TPB)
        cursor[k] = bucketBase[k] + excl[(size_t)b * NBK + k];
    __syncthreads();
    int nv = (pend - pstart) >> 2;
    for (int g = threadIdx.x; g < nv; g += TPB) {
        int p = pstart + (g << 2);
        v4i nets = *(const v4i*)(p2n + p);
        v4f xs = *(const v4f*)(pos + p);
        v4f ys = *(const v4f*)(pos + P + p);
        #pragma unroll
        for (int j = 0; j < 4; ++j) {
            int net = nets[j];
            unsigned off = atomicAdd(&cursor[net >> BK_SHIFT], 1u);
            recs[off] = pack_rec(xs[j], ys[j], net);
        }
    }
    for (int p = pstart + (nv << 2) + threadIdx.x; p < pend; p += TPB) {
        int net = p2n[p];
        unsigned off = atomicAdd(&cursor[net >> BK_SHIFT], 1u);
        recs[off] = pack_rec(pos[p], pos[P + p], net);
    }
}

// ---------------- Phase D: per-bucket LDS reduce ----------------
__global__ void reduce_kernel(const uint2* __restrict__ recs,
                              const unsigned* __restrict__ totals,
                              const unsigned* __restrict__ bucketBase,
                              const int* __restrict__ mask,
                              float* __restrict__ out, int num_nets) {
    int k = blockIdx.x;
    __shared__ unsigned tile[4 * BK_NETS];   // planes: mx, ~mn_x, my, ~mn_y
    for (int i = threadIdx.x; i < 4 * BK_NETS; i += TPB) tile[i] = 0;
    __syncthreads();
    unsigned base = bucketBase[k];
    unsigned cnt = totals[k];
    for (unsigned i = base + threadIdx.x; i < base + cnt; i += TPB) {
        uint2 r = recs[i];
        unsigned nl = ((r.x & 63u) << 5) | (r.y & 31u);
        unsigned ex = r.x & 0xFFFFFFC0u;
        unsigned ey = r.y & 0xFFFFFFE0u;
        atomicMax(&tile[nl], ex);
        atomicMax(&tile[BK_NETS + nl], (~ex) & 0xFFFFFFC0u);
        atomicMax(&tile[2 * BK_NETS + nl], ey);
        atomicMax(&tile[3 * BK_NETS + nl], (~ey) & 0xFFFFFFE0u);
    }
    __syncthreads();
    int gbase = k << BK_SHIFT;
    int nthis = min(BK_NETS, num_nets - gbase);
    float h = 0.0f;
    for (int n = threadIdx.x; n < nthis; n += TPB) {
        unsigned a = tile[n];
        if (a != 0u && mask[gbase + n] != 0) {
            float xmax = dec(a);
            float xmin = dec(~tile[BK_NETS + n]);     // low bits decode as |63
            float ymax = dec(tile[2 * BK_NETS + n]);
            float ymin = dec(~tile[3 * BK_NETS + n]);
            h += (xmax - xmin) + (ymax - ymin);
        }
    }
    #pragma unroll
    for (int off = 32; off > 0; off >>= 1)
        h += __shfl_down(h, off);
    __shared__ float s[TPB / 64];
    int wid = threadIdx.x >> 6;
    if ((threadIdx.x & 63) == 0) s[wid] = h;
    __syncthreads();
    if (threadIdx.x == 0) {
        float t = 0.0f;
        for (int w = 0; w < TPB / 64; ++w) t += s[w];
        atomicAdd(out, t);
    }
}

// ---------------- Fallback: global-atomic path ----------------
__device__ __forceinline__ void upd(unsigned* __restrict__ nets,
                                    float x, float y, int net) {
    unsigned ex = enc(x), ey = enc(y);
    unsigned* base = nets + ((size_t)net << 2);
    atomicMax(base + 0, ex);
    atomicMax(base + 1, ~ex);
    atomicMax(base + 2, ey);
    atomicMax(base + 3, ~ey);
}

__global__ void fb_pin_kernel(const float* __restrict__ pos,
                              const int* __restrict__ p2n,
                              unsigned* __restrict__ nets, int num_pins) {
    int i = blockIdx.x * blockDim.x + threadIdx.x;
    if (i >= num_pins) return;
    upd(nets, pos[i], pos[i + num_pins], p2n[i]);
}

__global__ void fb_net_kernel(const uint4* __restrict__ nets,
                              const int* __restrict__ mask,
                              float* __restrict__ out, int num_nets) {
    int i = blockIdx.x * blockDim.x + threadIdx.x;
    float h = 0.0f;
    if (i < num_nets) {
        uint4 v = nets[i];
        if (v.x != 0u && mask[i] != 0)
            h = (dec(v.x) - dec(~v.y)) + (dec(v.z) - dec(~v.w));
    }
    #pragma unroll
    for (int off = 32; off > 0; off >>= 1)
        h += __shfl_down(h, off);
    __shared__ float s[4];
    int wid = threadIdx.x >> 6;
    if ((threadIdx.x & 63) == 0) s[wid] = h;
    __syncthreads();
    if (threadIdx.x == 0)
        atomicAdd(out, s[0] + s[1] + s[2] + s[3]);
}

extern "C" void kernel_launch(void* const* d_in, const int* in_sizes, int n_in,
                              void* d_out, int out_size, void* d_ws, size_t ws_size,
                              hipStream_t stream) {
    const float* pos = (const float*)d_in[0];
    const int* p2n = (const int*)d_in[1];
    const int* mask = (const int*)d_in[2];
    const int P = in_sizes[0] / 2;
    const int N = in_sizes[2];

    const int NBK = (N + BK_NETS - 1) >> BK_SHIFT;
    const int NB = (P + CHUNK - 1) / CHUNK;
    const int NT = (NB + TILE_B - 1) / TILE_B;

    // ws: recs[P] (8B) | counts[NB*NBK] | tp[NT*NBK] | totals[NBK] | base[NBK]
    size_t recs_bytes = (size_t)P * sizeof(uint2);
    size_t counts_bytes = (size_t)NB * NBK * sizeof(unsigned);
    size_t tp_bytes = (size_t)NT * NBK * sizeof(unsigned);
    size_t need = recs_bytes + counts_bytes + tp_bytes +
                  2 * (size_t)NBK * sizeof(unsigned) + 256;

    hipMemsetAsync(d_out, 0, sizeof(float), stream);

    if (NBK <= MAX_BK && (P & 3) == 0 && ws_size >= need) {
        uint2* recs = (uint2*)d_ws;
        unsigned* counts = (unsigned*)((char*)d_ws + recs_bytes);
        unsigned* tp = counts + (size_t)NB * NBK;
        unsigned* totals = tp + (size_t)NT * NBK;
        unsigned* bucketBase = totals + NBK;

        int kb = (NBK + TPB - 1) / TPB;
        histo_kernel<<<NB, TPB, 0, stream>>>(p2n, counts, P, NBK);
        partial_kernel<<<dim3(kb, NT), TPB, 0, stream>>>(counts, tp, NB, NBK);
        tile_scan_kernel<<<kb, TPB, 0, stream>>>(tp, totals, NT, NBK);
        scan_buckets_kernel<<<1, TPB, 0, stream>>>(totals, bucketBase, NBK);
        exclify_kernel<<<dim3(kb, NT), TPB, 0, stream>>>(counts, tp, NB, NBK);
        scatter_kernel<<<NB, TPB, 0, stream>>>(pos, p2n, counts, bucketBase, recs, P, NBK);
        reduce_kernel<<<NBK, TPB, 0, stream>>>(recs, totals, bucketBase, mask,
                                               (float*)d_out, N);
    } else {
        unsigned* nets = (unsigned*)d_ws;
        hipMemsetAsync(d_ws, 0, (size_t)N * 4 * sizeof(unsigned), stream);
        fb_pin_kernel<<<(P + TPB - 1) / TPB, TPB, 0, stream>>>(pos, p2n, nets, P);
        fb_net_kernel<<<(N + TPB - 1) / TPB, TPB, 0, stream>>>((const uint4*)nets, mask,
                                                               (float*)d_out, N);
    }
}